// Round 3
// baseline (109.648 us; speedup 1.0000x reference)
//
#include <hip/hip_runtime.h>

// Segment attention pooling, MI355X (gfx950).
// convW ; segscan ; score_gemm (bf16 MFMA, K=64 stages, raw-barrier pipeline,
// counted waits, conflict-free LDS) ; pool.

#define SEP_ID 102
#define Bn 64
#define Sn 512
#define Hn 768
#define Mn 21
#define BS (Bn * Sn)

typedef __attribute__((ext_vector_type(8))) short bf16x8;
typedef __attribute__((ext_vector_type(8))) unsigned short u16x8;
typedef __attribute__((ext_vector_type(4))) float f32x4;

__device__ inline unsigned short f2bf(float x) {
  unsigned int u = __builtin_bit_cast(unsigned int, x);
  u += 0x7fffu + ((u >> 16) & 1u);   // RNE
  return (unsigned short)(u >> 16);
}

__device__ inline u16x8 cvt8(float4 a, float4 b) {
  u16x8 r;
  r[0] = f2bf(a.x); r[1] = f2bf(a.y); r[2] = f2bf(a.z); r[3] = f2bf(a.w);
  r[4] = f2bf(b.x); r[5] = f2bf(b.y); r[6] = f2bf(b.z); r[7] = f2bf(b.w);
  return r;
}

__device__ inline float tanh_fast(float x) {
  float e = __builtin_amdgcn_exp2f(x * 2.885390081777927f); // 2*log2(e)
  return 1.f - 2.f * __builtin_amdgcn_rcpf(e + 1.f);
}

// ---------------- kernel 1: W fp32 -> bf16
__global__ void convw_kernel(const float* __restrict__ W, unsigned short* __restrict__ WB) {
  int i = (blockIdx.x * 256 + threadIdx.x) * 4;
  float4 x = *reinterpret_cast<const float4*>(&W[i]);
  ushort4 u;
  u.x = f2bf(x.x); u.y = f2bf(x.y); u.z = f2bf(x.z); u.w = f2bf(x.w);
  *reinterpret_cast<ushort4*>(&WB[i]) = u;
}

// ---------------- kernel 2: per-batch segment scan
__global__ void segscan_kernel(const int* __restrict__ ids,
                               unsigned char* __restrict__ segv,
                               int* __restrict__ nsep) {
  int b = blockIdx.x;
  int s = threadIdx.x;
  __shared__ int cs[Sn];
  int sep = (ids[b * Sn + s] == SEP_ID) ? 1 : 0;
  cs[s] = sep;
  __syncthreads();
  for (int off = 1; off < Sn; off <<= 1) {
    int add = (s >= off) ? cs[s - off] : 0;
    __syncthreads();
    cs[s] += add;
    __syncthreads();
  }
  int csum = cs[s];
  int nb = cs[Sn - 1];
  int seg = csum - sep;
  bool valid = (!sep) && (s >= 1) && (seg < nb) && (seg < Mn);
  segv[b * Sn + s] = valid ? (unsigned char)seg : (unsigned char)0xFF;
  if (s == 0) nsep[b] = nb;
}

// ---------------- kernel 3: scores = v . tanh(hidden @ W^T + b)
// 512 thr = 8 waves (1M x 8N), BM=64 full-N, K staged 64 at a time (12 stages),
// LDS double-buffered stride-72-short layout (conflict-free b128 r/w),
// raw s_barrier + lgkmcnt(0) only (vmem loads stay in flight across barriers).
__global__ __launch_bounds__(512) void score_gemm_kernel(
    const float* __restrict__ hid, const unsigned short* __restrict__ WB,
    const float* __restrict__ bbias, const float* __restrict__ vvec,
    float* __restrict__ scores) {
  __shared__ __align__(16) unsigned short As[2][64 * 72];  // 144B row stride
  __shared__ float vLds[Hn];
  __shared__ float bLds[Hn];
  __shared__ float scpart[8][64];

  const int t = threadIdx.x;
  const size_t rowBase = (size_t)blockIdx.x * 64;
  const int wid = t >> 6, lane = t & 63;
  const int l15 = lane & 15, l4 = lane >> 4;
  const int colBase = wid * 96;

  for (int i = t; i < Hn; i += 512) { vLds[i] = vvec[i]; bLds[i] = bbias[i]; }

  // staging: thread t owns (row = t>>3, kq = t&7) -> one 16B chunk per stage
  const int srow = t >> 3, skq = t & 7;
  const float* hrow = &hid[(rowBase + srow) * Hn + skq * 8];
  const int ldsWoff = srow * 72 + skq * 8;              // shorts
  // frag read base: rows mi*16+l15 (stride 72 shorts), chunk kq = 4h + l4
  const int aroff = l15 * 72 + l4 * 8;                  // + mi*1152 + h*32
  const unsigned short* bptr = &WB[(size_t)(colBase + l15) * Hn + l4 * 8];

  f32x4 acc[4][6];
#pragma unroll
  for (int mi = 0; mi < 4; ++mi)
#pragma unroll
    for (int ni = 0; ni < 6; ++ni) acc[mi][ni] = (f32x4){0.f, 0.f, 0.f, 0.f};

  // ---- prologue: A(0) -> LDS[0]; bcur = B(0,h0); araw = A(1)
  float4 p0 = *reinterpret_cast<const float4*>(hrow);
  float4 p1 = *reinterpret_cast<const float4*>(hrow + 4);
  bf16x8 bcur[6];
#pragma unroll
  for (int ni = 0; ni < 6; ++ni)
    bcur[ni] = *reinterpret_cast<const bf16x8*>(bptr + (size_t)ni * 16 * Hn);
  float4 ar0a = *reinterpret_cast<const float4*>(hrow + 64);
  float4 ar0b = *reinterpret_cast<const float4*>(hrow + 68);
  float4 ar1a, ar1b;
  *reinterpret_cast<u16x8*>(&As[0][ldsWoff]) = cvt8(p0, p1);
  asm volatile("s_waitcnt lgkmcnt(0)" ::: "memory");
  __builtin_amdgcn_s_barrier();
  __builtin_amdgcn_sched_barrier(0);

#define STAGE(s_, buf_, arA_, arB_, nxA_, nxB_)                                \
  {                                                                            \
    const int s_c = (s_);                                                      \
    bf16x8 af0[4];                                                             \
    _Pragma("unroll")                                                          \
    for (int mi = 0; mi < 4; ++mi)                                             \
      af0[mi] = *reinterpret_cast<const bf16x8*>(&As[buf_][mi * 1152 + aroff]);\
    {                                                                          \
      const int s2 = (s_c + 2 > 11) ? 11 : s_c + 2;                            \
      nxA_ = *reinterpret_cast<const float4*>(hrow + s2 * 64);                 \
      nxB_ = *reinterpret_cast<const float4*>(hrow + s2 * 64 + 4);             \
    }                                                                          \
    *reinterpret_cast<u16x8*>(&As[(buf_) ^ 1][ldsWoff]) = cvt8(arA_, arB_);    \
    bf16x8 bnxt[6];                                                            \
    _Pragma("unroll")                                                          \
    for (int ni = 0; ni < 6; ++ni)                                             \
      bnxt[ni] = *reinterpret_cast<const bf16x8*>(                             \
          bptr + (size_t)ni * 16 * Hn + s_c * 64 + 32);                        \
    __builtin_amdgcn_s_setprio(1);                                             \
    _Pragma("unroll")                                                          \
    for (int mi = 0; mi < 4; ++mi)                                             \
      _Pragma("unroll")                                                        \
      for (int ni = 0; ni < 6; ++ni)                                           \
        acc[mi][ni] = __builtin_amdgcn_mfma_f32_16x16x32_bf16(                 \
            af0[mi], bcur[ni], acc[mi][ni], 0, 0, 0);                          \
    __builtin_amdgcn_s_setprio(0);                                             \
    bf16x8 af1[4];                                                             \
    _Pragma("unroll")                                                          \
    for (int mi = 0; mi < 4; ++mi)                                             \
      af1[mi] = *reinterpret_cast<const bf16x8*>(                              \
          &As[buf_][mi * 1152 + aroff + 32]);                                  \
    {                                                                          \
      const int s1 = (s_c + 1 > 11) ? 11 : s_c + 1;                            \
      _Pragma("unroll")                                                        \
      for (int ni = 0; ni < 6; ++ni)                                           \
        bcur[ni] = *reinterpret_cast<const bf16x8*>(                           \
            bptr + (size_t)ni * 16 * Hn + s1 * 64);                            \
    }                                                                          \
    __builtin_amdgcn_s_setprio(1);                                             \
    _Pragma("unroll")                                                          \
    for (int mi = 0; mi < 4; ++mi)                                             \
      _Pragma("unroll")                                                        \
      for (int ni = 0; ni < 6; ++ni)                                           \
        acc[mi][ni] = __builtin_amdgcn_mfma_f32_16x16x32_bf16(                 \
            af1[mi], bnxt[ni], acc[mi][ni], 0, 0, 0);                          \
    __builtin_amdgcn_s_setprio(0);                                             \
    __builtin_amdgcn_sched_barrier(0);                                         \
    asm volatile("s_waitcnt lgkmcnt(0)" ::: "memory");                         \
    __builtin_amdgcn_s_barrier();                                              \
    __builtin_amdgcn_sched_barrier(0);                                         \
  }

  for (int ss = 0; ss < 12; ss += 2) {
    STAGE(ss,     0, ar0a, ar0b, ar1a, ar1b)
    STAGE(ss + 1, 1, ar1a, ar1b, ar0a, ar0b)
  }
#undef STAGE

  // ---- fused epilogue
  float sc[4][4];
#pragma unroll
  for (int mi = 0; mi < 4; ++mi)
#pragma unroll
    for (int r = 0; r < 4; ++r) sc[mi][r] = 0.f;
#pragma unroll
  for (int mi = 0; mi < 4; ++mi)
#pragma unroll
    for (int ni = 0; ni < 6; ++ni) {
      int col = colBase + ni * 16 + l15;
      float vv = vLds[col];
      float bb = bLds[col];
#pragma unroll
      for (int r = 0; r < 4; ++r)
        sc[mi][r] += tanh_fast(acc[mi][ni][r] + bb) * vv;
    }
#pragma unroll
  for (int off = 1; off < 16; off <<= 1)
#pragma unroll
    for (int mi = 0; mi < 4; ++mi)
#pragma unroll
      for (int r = 0; r < 4; ++r)
        sc[mi][r] += __shfl_xor(sc[mi][r], off, 64);
  if (l15 == 0) {
#pragma unroll
    for (int mi = 0; mi < 4; ++mi)
#pragma unroll
      for (int r = 0; r < 4; ++r)
        scpart[wid][mi * 16 + l4 * 4 + r] = sc[mi][r];
  }
  __syncthreads();
  if (t < 64) {
    float s = 0.f;
#pragma unroll
    for (int w = 0; w < 8; ++w) s += scpart[w][t];
    scores[rowBase + t] = s;
  }
}

// ---------------- kernel 4: per-(b,m) segment softmax + pooling
__global__ __launch_bounds__(256) void pool_kernel(
    const float* __restrict__ hid, const float* __restrict__ scores,
    const unsigned char* __restrict__ segv, const int* __restrict__ nsep,
    float* __restrict__ out) {
  int bm = blockIdx.x;
  int b = bm / Mn, m = bm % Mn;
  int t = threadIdx.x;
  __shared__ float wLds[Sn];
  __shared__ float red[256];
  __shared__ int ired[256];
  const float NEG = -1e30f;

  int base = b * Sn;
  unsigned char mg = (unsigned char)m;
  unsigned char g0 = segv[base + t], g1 = segv[base + 256 + t];
  bool v0 = (g0 == mg), v1 = (g1 == mg);
  float s0 = v0 ? scores[base + t] : NEG;
  float s1 = v1 ? scores[base + 256 + t] : NEG;

  red[t] = fmaxf(s0, s1);
  __syncthreads();
  for (int o = 128; o > 0; o >>= 1) {
    if (t < o) red[t] = fmaxf(red[t], red[t + o]);
    __syncthreads();
  }
  float gmax = red[0];
  __syncthreads();

  size_t obase = (size_t)bm * Hn;
  if (gmax <= -0.5e30f) {
    int nb = nsep[b];
    float a0 = 0.f, a1 = 0.f, a2 = 0.f;
    if (m == 0 && nb == 0) {
      const float* hp = hid + (size_t)base * Hn;
      a0 = hp[t]; a1 = hp[t + 256]; a2 = hp[t + 512];
    }
    out[obase + t] = a0; out[obase + 256 + t] = a1; out[obase + 512 + t] = a2;
    return;
  }

  float e0 = v0 ? expf(s0 - gmax) : 0.f;
  float e1 = v1 ? expf(s1 - gmax) : 0.f;
  red[t] = e0 + e1;
  __syncthreads();
  for (int o = 128; o > 0; o >>= 1) {
    if (t < o) red[t] += red[t + o];
    __syncthreads();
  }
  float inv = 1.f / red[0];
  __syncthreads();
  wLds[t] = e0 * inv;
  wLds[256 + t] = e1 * inv;

  ired[t] = min(v0 ? t : 0x7fffffff, v1 ? (256 + t) : 0x7fffffff);
  __syncthreads();
  for (int o = 128; o > 0; o >>= 1) {
    if (t < o) ired[t] = min(ired[t], ired[t + o]);
    __syncthreads();
  }
  int start = ired[0];
  __syncthreads();
  ired[t] = max(v0 ? t : -1, v1 ? (256 + t) : -1);
  __syncthreads();
  for (int o = 128; o > 0; o >>= 1) {
    if (t < o) ired[t] = max(ired[t], ired[t + o]);
    __syncthreads();
  }
  int end = ired[0];
  __syncthreads();

  float a0 = 0.f, a1 = 0.f, a2 = 0.f;
  for (int s = start; s <= end; ++s) {
    float w = wLds[s];
    if (w != 0.f) {
      const float* hp = hid + (size_t)(base + s) * Hn;
      a0 += w * hp[t];
      a1 += w * hp[t + 256];
      a2 += w * hp[t + 512];
    }
  }
  out[obase + t] = a0;
  out[obase + 256 + t] = a1;
  out[obase + 512 + t] = a2;
}

// ---------------- launch
extern "C" void kernel_launch(void* const* d_in, const int* in_sizes, int n_in,
                              void* d_out, int out_size, void* d_ws, size_t ws_size,
                              hipStream_t stream) {
  const float* hidden = (const float*)d_in[0];
  const int* ids      = (const int*)d_in[1];
  const float* W      = (const float*)d_in[2];
  const float* bbias  = (const float*)d_in[3];
  const float* vvec   = (const float*)d_in[4];

  char* ws = (char*)d_ws;
  unsigned short* WB   = (unsigned short*)(ws);
  float* scores        = (float*)(ws + 1179648);
  unsigned char* segv  = (unsigned char*)(ws + 1310720);
  int* nsep            = (int*)(ws + 1343488);

  convw_kernel<<<576, 256, 0, stream>>>(W, WB);
  segscan_kernel<<<Bn, Sn, 0, stream>>>(ids, segv, nsep);
  score_gemm_kernel<<<BS / 64, 512, 0, stream>>>(hidden, WB, bbias, vvec, scores);
  pool_kernel<<<Bn * Mn, 256, 0, stream>>>(hidden, scores, segv, nsep, (float*)d_out);
}

// Round 4
// 105.940 us; speedup vs baseline: 1.0350x; 1.0350x over previous
//
#include <hip/hip_runtime.h>

// Segment attention pooling, MI355X (gfx950).
// convW ; segscan ; score_gemm (A-tile fully LDS-resident, 16 waves/block,
// narrow per-wave col slices -> small acc, chunked A-load pipeline) ; pool.

#define SEP_ID 102
#define Bn 64
#define Sn 512
#define Hn 768
#define Mn 21
#define BS (Bn * Sn)

typedef __attribute__((ext_vector_type(8))) short bf16x8;
typedef __attribute__((ext_vector_type(8))) unsigned short u16x8;
typedef __attribute__((ext_vector_type(4))) float f32x4;

__device__ inline unsigned short f2bf(float x) {
  unsigned int u = __builtin_bit_cast(unsigned int, x);
  u += 0x7fffu + ((u >> 16) & 1u);   // RNE
  return (unsigned short)(u >> 16);
}

__device__ inline u16x8 cvt8(float4 a, float4 b) {
  u16x8 r;
  r[0] = f2bf(a.x); r[1] = f2bf(a.y); r[2] = f2bf(a.z); r[3] = f2bf(a.w);
  r[4] = f2bf(b.x); r[5] = f2bf(b.y); r[6] = f2bf(b.z); r[7] = f2bf(b.w);
  return r;
}

__device__ inline float tanh_fast(float x) {
  float e = __builtin_amdgcn_exp2f(x * 2.885390081777927f); // 2*log2(e)
  return 1.f - 2.f * __builtin_amdgcn_rcpf(e + 1.f);
}

// ---------------- kernel 1: W fp32 -> bf16
__global__ void convw_kernel(const float* __restrict__ W, unsigned short* __restrict__ WB) {
  int i = (blockIdx.x * 256 + threadIdx.x) * 4;
  float4 x = *reinterpret_cast<const float4*>(&W[i]);
  ushort4 u;
  u.x = f2bf(x.x); u.y = f2bf(x.y); u.z = f2bf(x.z); u.w = f2bf(x.w);
  *reinterpret_cast<ushort4*>(&WB[i]) = u;
}

// ---------------- kernel 2: per-batch segment scan
__global__ void segscan_kernel(const int* __restrict__ ids,
                               unsigned char* __restrict__ segv,
                               int* __restrict__ nsep) {
  int b = blockIdx.x;
  int s = threadIdx.x;
  __shared__ int cs[Sn];
  int sep = (ids[b * Sn + s] == SEP_ID) ? 1 : 0;
  cs[s] = sep;
  __syncthreads();
  for (int off = 1; off < Sn; off <<= 1) {
    int add = (s >= off) ? cs[s - off] : 0;
    __syncthreads();
    cs[s] += add;
    __syncthreads();
  }
  int csum = cs[s];
  int nb = cs[Sn - 1];
  int seg = csum - sep;
  bool valid = (!sep) && (s >= 1) && (seg < nb) && (seg < Mn);
  segv[b * Sn + s] = valid ? (unsigned char)seg : (unsigned char)0xFF;
  if (s == 0) nsep[b] = nb;
}

// ---------------- kernel 3: scores = v . tanh(hidden @ W^T + b)
// 1024 thr = 16 waves. Block tile: 64 rows x 768 cols. Wave: 64 rows x 48 cols.
// A tile (64x768 bf16, 96KB) lives in LDS for the whole kernel, loaded in 6
// K-chunks of 128 (load of chunk c+1 overlaps compute on chunk c; raw
// s_barrier + lgkmcnt(0) only). 16B-chunk XOR swizzle (c ^ (row&7)) on both
// the staging writes and frag reads -> conflict-free b128 ops.
// acc = 48 VGPR/lane -> ~115 total -> 4 waves/SIMD.
__global__ __launch_bounds__(1024, 4) void score_gemm_kernel(
    const float* __restrict__ hid, const unsigned short* __restrict__ WB,
    const float* __restrict__ bbias, const float* __restrict__ vvec,
    float* __restrict__ scores) {
  __shared__ __align__(16) unsigned short As[64 * 768];   // 98304 B
  __shared__ float scpart[16][64];                         //  4096 B

  const int t = threadIdx.x;
  const size_t rowBase = (size_t)blockIdx.x * 64;
  const int wid = t >> 6, lane = t & 63;
  const int l15 = lane & 15, l4 = lane >> 4;
  const int colBase = wid * 48;

  // A staging map: thread t owns (row = t>>4, 16B-chunk cloc = t&15) per K-chunk
  const int srow = t >> 4;          // 0..63
  const int scloc = t & 15;         // 0..15
  const float* hsrc = &hid[(rowBase + srow) * Hn + scloc * 8];
  unsigned short* const arow = &As[srow * Hn];
  const int swz = srow & 7;

  // B pointer: cols colBase + ni*16 + l15, k chunk l4*8
  const unsigned short* bptr = &WB[(size_t)(colBase + l15) * Hn + l4 * 8];

  // A frag read base: row mi*16 + l15 (swizzle uses l15&7), chunk kk*4 + l4
  const unsigned short* const afrow = &As[l15 * Hn];
  const int aswz = l15 & 7;

  f32x4 acc[4][3];
#pragma unroll
  for (int mi = 0; mi < 4; ++mi)
#pragma unroll
    for (int ni = 0; ni < 3; ++ni) acc[mi][ni] = (f32x4){0.f, 0.f, 0.f, 0.f};

  // ---- prologue: stage A chunk 0, load B frags for kk=0
  {
    float4 a0 = *reinterpret_cast<const float4*>(hsrc);
    float4 a1 = *reinterpret_cast<const float4*>(hsrc + 4);
    *reinterpret_cast<u16x8*>(arow + (scloc ^ swz) * 8) = cvt8(a0, a1);
  }
  bf16x8 bcur[3], bnxt[3];
#pragma unroll
  for (int ni = 0; ni < 3; ++ni)
    bcur[ni] = *reinterpret_cast<const bf16x8*>(bptr + (size_t)ni * 16 * Hn);
  asm volatile("s_waitcnt lgkmcnt(0)" ::: "memory");
  __builtin_amdgcn_s_barrier();
  __builtin_amdgcn_sched_barrier(0);

#pragma unroll
  for (int cc = 0; cc < 6; ++cc) {
    // issue next A-chunk loads first (HBM latency hides under 4 k-steps)
    float4 n0, n1;
    if (cc < 5) {
      n0 = *reinterpret_cast<const float4*>(hsrc + (cc + 1) * 128);
      n1 = *reinterpret_cast<const float4*>(hsrc + (cc + 1) * 128 + 4);
    }
#pragma unroll
    for (int k4 = 0; k4 < 4; ++k4) {
      const int kk = cc * 4 + k4;
      bf16x8 af[4];
#pragma unroll
      for (int mi = 0; mi < 4; ++mi)
        af[mi] = *reinterpret_cast<const bf16x8*>(
            &afrow[mi * 16 * Hn + (((kk * 4 + l4) ^ aswz)) * 8]);
      if (kk < 23) {
#pragma unroll
        for (int ni = 0; ni < 3; ++ni)
          bnxt[ni] = *reinterpret_cast<const bf16x8*>(
              bptr + (size_t)ni * 16 * Hn + (kk + 1) * 32);
      }
      __builtin_amdgcn_s_setprio(1);
#pragma unroll
      for (int mi = 0; mi < 4; ++mi)
#pragma unroll
        for (int ni = 0; ni < 3; ++ni)
          acc[mi][ni] = __builtin_amdgcn_mfma_f32_16x16x32_bf16(
              af[mi], bcur[ni], acc[mi][ni], 0, 0, 0);
      __builtin_amdgcn_s_setprio(0);
#pragma unroll
      for (int ni = 0; ni < 3; ++ni) bcur[ni] = bnxt[ni];
    }
    if (cc < 5) {
      // write next A chunk, then barrier (LDS-drain only; vmem stays in flight)
      *reinterpret_cast<u16x8*>(
          arow + ((((cc + 1) * 16 + scloc) ^ swz)) * 8) = cvt8(n0, n1);
      asm volatile("s_waitcnt lgkmcnt(0)" ::: "memory");
      __builtin_amdgcn_s_barrier();
      __builtin_amdgcn_sched_barrier(0);
    }
  }

  // ---- fused epilogue: tanh(pre + b) * v over the wave's 48 cols
  float sc[4][4];
#pragma unroll
  for (int mi = 0; mi < 4; ++mi)
#pragma unroll
    for (int r = 0; r < 4; ++r) sc[mi][r] = 0.f;
#pragma unroll
  for (int ni = 0; ni < 3; ++ni) {
    int col = colBase + ni * 16 + l15;
    float vv = vvec[col];
    float bb = bbias[col];
#pragma unroll
    for (int mi = 0; mi < 4; ++mi)
#pragma unroll
      for (int r = 0; r < 4; ++r)
        sc[mi][r] += tanh_fast(acc[mi][ni][r] + bb) * vv;
  }
#pragma unroll
  for (int off = 1; off < 16; off <<= 1)
#pragma unroll
    for (int mi = 0; mi < 4; ++mi)
#pragma unroll
      for (int r = 0; r < 4; ++r)
        sc[mi][r] += __shfl_xor(sc[mi][r], off, 64);
  if (l15 == 0) {
#pragma unroll
    for (int mi = 0; mi < 4; ++mi)
#pragma unroll
      for (int r = 0; r < 4; ++r)
        scpart[wid][mi * 16 + l4 * 4 + r] = sc[mi][r];
  }
  __syncthreads();
  if (t < 64) {
    float s = 0.f;
#pragma unroll
    for (int w = 0; w < 16; ++w) s += scpart[w][t];
    scores[rowBase + t] = s;
  }
}

// ---------------- kernel 4: per-(b,m) segment softmax + pooling
__global__ __launch_bounds__(256) void pool_kernel(
    const float* __restrict__ hid, const float* __restrict__ scores,
    const unsigned char* __restrict__ segv, const int* __restrict__ nsep,
    float* __restrict__ out) {
  int bm = blockIdx.x;
  int b = bm / Mn, m = bm % Mn;
  int t = threadIdx.x;
  __shared__ float wLds[Sn];
  __shared__ float red[256];
  __shared__ int ired[256];
  const float NEG = -1e30f;

  int base = b * Sn;
  unsigned char mg = (unsigned char)m;
  unsigned char g0 = segv[base + t], g1 = segv[base + 256 + t];
  bool v0 = (g0 == mg), v1 = (g1 == mg);
  float s0 = v0 ? scores[base + t] : NEG;
  float s1 = v1 ? scores[base + 256 + t] : NEG;

  red[t] = fmaxf(s0, s1);
  __syncthreads();
  for (int o = 128; o > 0; o >>= 1) {
    if (t < o) red[t] = fmaxf(red[t], red[t + o]);
    __syncthreads();
  }
  float gmax = red[0];
  __syncthreads();

  size_t obase = (size_t)bm * Hn;
  if (gmax <= -0.5e30f) {
    int nb = nsep[b];
    float a0 = 0.f, a1 = 0.f, a2 = 0.f;
    if (m == 0 && nb == 0) {
      const float* hp = hid + (size_t)base * Hn;
      a0 = hp[t]; a1 = hp[t + 256]; a2 = hp[t + 512];
    }
    out[obase + t] = a0; out[obase + 256 + t] = a1; out[obase + 512 + t] = a2;
    return;
  }

  float e0 = v0 ? expf(s0 - gmax) : 0.f;
  float e1 = v1 ? expf(s1 - gmax) : 0.f;
  red[t] = e0 + e1;
  __syncthreads();
  for (int o = 128; o > 0; o >>= 1) {
    if (t < o) red[t] += red[t + o];
    __syncthreads();
  }
  float inv = 1.f / red[0];
  __syncthreads();
  wLds[t] = e0 * inv;
  wLds[256 + t] = e1 * inv;

  ired[t] = min(v0 ? t : 0x7fffffff, v1 ? (256 + t) : 0x7fffffff);
  __syncthreads();
  for (int o = 128; o > 0; o >>= 1) {
    if (t < o) ired[t] = min(ired[t], ired[t + o]);
    __syncthreads();
  }
  int start = ired[0];
  __syncthreads();
  ired[t] = max(v0 ? t : -1, v1 ? (256 + t) : -1);
  __syncthreads();
  for (int o = 128; o > 0; o >>= 1) {
    if (t < o) ired[t] = max(ired[t], ired[t + o]);
    __syncthreads();
  }
  int end = ired[0];
  __syncthreads();

  float a0 = 0.f, a1 = 0.f, a2 = 0.f;
  for (int s = start; s <= end; ++s) {
    float w = wLds[s];
    if (w != 0.f) {
      const float* hp = hid + (size_t)(base + s) * Hn;
      a0 += w * hp[t];
      a1 += w * hp[t + 256];
      a2 += w * hp[t + 512];
    }
  }
  out[obase + t] = a0;
  out[obase + 256 + t] = a1;
  out[obase + 512 + t] = a2;
}

// ---------------- launch
extern "C" void kernel_launch(void* const* d_in, const int* in_sizes, int n_in,
                              void* d_out, int out_size, void* d_ws, size_t ws_size,
                              hipStream_t stream) {
  const float* hidden = (const float*)d_in[0];
  const int* ids      = (const int*)d_in[1];
  const float* W      = (const float*)d_in[2];
  const float* bbias  = (const float*)d_in[3];
  const float* vvec   = (const float*)d_in[4];

  char* ws = (char*)d_ws;
  unsigned short* WB   = (unsigned short*)(ws);
  float* scores        = (float*)(ws + 1179648);
  unsigned char* segv  = (unsigned char*)(ws + 1310720);
  int* nsep            = (int*)(ws + 1343488);

  convw_kernel<<<576, 256, 0, stream>>>(W, WB);
  segscan_kernel<<<Bn, Sn, 0, stream>>>(ids, segv, nsep);
  score_gemm_kernel<<<BS / 64, 1024, 0, stream>>>(hidden, WB, bbias, vvec, scores);
  pool_kernel<<<Bn * Mn, 256, 0, stream>>>(hidden, scores, segv, nsep, (float*)d_out);
}

// Round 5
// 78.033 us; speedup vs baseline: 1.4052x; 1.3576x over previous
//
#include <hip/hip_runtime.h>

// Segment attention pooling, MI355X (gfx950).
// convw_pack (fp32 W -> bf16 in MFMA-fragment-packed order) ; segscan ;
// score_gemm (whole A-tile LDS-resident, barrier-free K-loop, 16 waves,
// lane-contiguous B loads, depth-2 B prefetch) ; pool.

#define SEP_ID 102
#define Bn 64
#define Sn 512
#define Hn 768
#define Mn 21
#define BS (Bn * Sn)

typedef __attribute__((ext_vector_type(8))) short bf16x8;
typedef __attribute__((ext_vector_type(8))) unsigned short u16x8;
typedef __attribute__((ext_vector_type(4))) float f32x4;

__device__ inline unsigned short f2bf(float x) {
  unsigned int u = __builtin_bit_cast(unsigned int, x);
  u += 0x7fffu + ((u >> 16) & 1u);   // RNE
  return (unsigned short)(u >> 16);
}

__device__ inline u16x8 cvt8(float4 a, float4 b) {
  u16x8 r;
  r[0] = f2bf(a.x); r[1] = f2bf(a.y); r[2] = f2bf(a.z); r[3] = f2bf(a.w);
  r[4] = f2bf(b.x); r[5] = f2bf(b.y); r[6] = f2bf(b.z); r[7] = f2bf(b.w);
  return r;
}

__device__ inline float tanh_fast(float x) {
  float e = __builtin_amdgcn_exp2f(x * 2.885390081777927f); // 2*log2(e)
  return 1.f - 2.f * __builtin_amdgcn_rcpf(e + 1.f);
}

// ---------------- kernel 1: W fp32 -> bf16, packed in MFMA B-fragment order.
// chunk c = (ntile*24 + kstep)*64 + lane; lane = l4*16 + l15;
// holds W[col = ntile*16 + l15][k = kstep*32 + l4*8 .. +8].
// So in score_gemm a wave's B-load is lane-contiguous: base + lane*16B.
__global__ void convw_kernel(const float* __restrict__ W, unsigned short* __restrict__ WBp) {
  int c = blockIdx.x * 256 + threadIdx.x;   // 73728 chunks, grid 288
  int nt = c / 1536;                        // 1536 = 24*64
  int r  = c % 1536;
  int ks = r >> 6;
  int ln = r & 63;
  int col = nt * 16 + (ln & 15);
  int k0  = ks * 32 + (ln >> 4) * 8;
  const float* src = &W[col * Hn + k0];
  float4 a = *reinterpret_cast<const float4*>(src);
  float4 b = *reinterpret_cast<const float4*>(src + 4);
  *reinterpret_cast<u16x8*>(&WBp[(size_t)c * 8]) = cvt8(a, b);
}

// ---------------- kernel 2: per-batch segment scan
__global__ void segscan_kernel(const int* __restrict__ ids,
                               unsigned char* __restrict__ segv,
                               int* __restrict__ nsep) {
  int b = blockIdx.x;
  int s = threadIdx.x;
  __shared__ int cs[Sn];
  int sep = (ids[b * Sn + s] == SEP_ID) ? 1 : 0;
  cs[s] = sep;
  __syncthreads();
  for (int off = 1; off < Sn; off <<= 1) {
    int add = (s >= off) ? cs[s - off] : 0;
    __syncthreads();
    cs[s] += add;
    __syncthreads();
  }
  int csum = cs[s];
  int nb = cs[Sn - 1];
  int seg = csum - sep;
  bool valid = (!sep) && (s >= 1) && (seg < nb) && (seg < Mn);
  segv[b * Sn + s] = valid ? (unsigned char)seg : (unsigned char)0xFF;
  if (s == 0) nsep[b] = nb;
}

// ---------------- kernel 3: scores = v . tanh(hidden @ W^T + b)
// 1024 thr = 16 waves, block = 64 rows x 768 cols, wave = 64 rows x 48 cols.
// Prologue: stage whole 64x768 A-tile (fp32->bf16) into LDS, ONE barrier.
// K-loop: 24 steps, NO barriers (A read-only; waves free-run and desync),
// B loaded lane-contiguous from packed WBp with depth-2 register prefetch.
__global__ __launch_bounds__(1024, 4) void score_gemm_kernel(
    const float* __restrict__ hid, const unsigned short* __restrict__ WBp,
    const float* __restrict__ bbias, const float* __restrict__ vvec,
    float* __restrict__ scores) {
  __shared__ __align__(16) unsigned short As[64 * 768];   // 98304 B
  __shared__ float scpart[16][64];

  const int t = threadIdx.x;
  const size_t rowBase = (size_t)blockIdx.x * 64;
  const int wid = t >> 6, lane = t & 63;
  const int l15 = lane & 15, l4 = lane >> 4;
  const int colBase = wid * 48;

  // ---- prologue: stage A (each thread: row = t>>4, 16B chunk scloc = t&15,
  // one chunk per each of the 6 K-chunks of 128). XOR-swizzle chunk ^ (row&7).
  {
    const int srow = t >> 4;
    const int scloc = t & 15;
    const float* hsrc = &hid[(rowBase + srow) * Hn + scloc * 8];
    unsigned short* const arow = &As[srow * Hn];
    const int swz = srow & 7;
    float4 p[6][2];
#pragma unroll
    for (int cc = 0; cc < 6; ++cc) {
      p[cc][0] = *reinterpret_cast<const float4*>(hsrc + cc * 128);
      p[cc][1] = *reinterpret_cast<const float4*>(hsrc + cc * 128 + 4);
    }
#pragma unroll
    for (int cc = 0; cc < 6; ++cc)
      *reinterpret_cast<u16x8*>(arow + ((cc * 16 + scloc) ^ swz) * 8) =
          cvt8(p[cc][0], p[cc][1]);
  }
  __syncthreads();

  // A frag read base: row = mi*16 + l15, chunk = (kk*4 + l4) ^ (l15&7)
  const unsigned short* const afrow = &As[l15 * Hn];
  const int aswz = l15 & 7;
  // B: packed fragment chunks, ntile = wid*3 + ni, per-kstep stride 512 shorts
  const unsigned short* bp0 = &WBp[((size_t)(wid * 3 + 0) * 24 * 64 + lane) * 8];
  const unsigned short* bp1 = &WBp[((size_t)(wid * 3 + 1) * 24 * 64 + lane) * 8];
  const unsigned short* bp2 = &WBp[((size_t)(wid * 3 + 2) * 24 * 64 + lane) * 8];

  f32x4 acc[4][3];
#pragma unroll
  for (int mi = 0; mi < 4; ++mi)
#pragma unroll
    for (int ni = 0; ni < 3; ++ni) acc[mi][ni] = (f32x4){0.f, 0.f, 0.f, 0.f};

  bf16x8 b0[3], b1[3], b2[3];
  b0[0] = *reinterpret_cast<const bf16x8*>(bp0);
  b0[1] = *reinterpret_cast<const bf16x8*>(bp1);
  b0[2] = *reinterpret_cast<const bf16x8*>(bp2);
  b1[0] = *reinterpret_cast<const bf16x8*>(bp0 + 512);
  b1[1] = *reinterpret_cast<const bf16x8*>(bp1 + 512);
  b1[2] = *reinterpret_cast<const bf16x8*>(bp2 + 512);

#pragma unroll
  for (int kk = 0; kk < 24; ++kk) {
    bf16x8 af[4];
#pragma unroll
    for (int mi = 0; mi < 4; ++mi)
      af[mi] = *reinterpret_cast<const bf16x8*>(
          &afrow[mi * 16 * Hn + (((kk * 4 + l4)) ^ aswz) * 8]);
    if (kk + 2 < 24) {
      b2[0] = *reinterpret_cast<const bf16x8*>(bp0 + (kk + 2) * 512);
      b2[1] = *reinterpret_cast<const bf16x8*>(bp1 + (kk + 2) * 512);
      b2[2] = *reinterpret_cast<const bf16x8*>(bp2 + (kk + 2) * 512);
    }
    __builtin_amdgcn_s_setprio(1);
#pragma unroll
    for (int mi = 0; mi < 4; ++mi)
#pragma unroll
      for (int ni = 0; ni < 3; ++ni)
        acc[mi][ni] = __builtin_amdgcn_mfma_f32_16x16x32_bf16(
            af[mi], b0[ni], acc[mi][ni], 0, 0, 0);
    __builtin_amdgcn_s_setprio(0);
#pragma unroll
    for (int ni = 0; ni < 3; ++ni) { b0[ni] = b1[ni]; b1[ni] = b2[ni]; }
  }

  // ---- fused epilogue: tanh(pre + b) * v over the wave's 48 cols
  float sc[4][4];
#pragma unroll
  for (int mi = 0; mi < 4; ++mi)
#pragma unroll
    for (int r = 0; r < 4; ++r) sc[mi][r] = 0.f;
#pragma unroll
  for (int ni = 0; ni < 3; ++ni) {
    int col = colBase + ni * 16 + l15;
    float vv = vvec[col];
    float bb = bbias[col];
#pragma unroll
    for (int mi = 0; mi < 4; ++mi)
#pragma unroll
      for (int r = 0; r < 4; ++r)
        sc[mi][r] += tanh_fast(acc[mi][ni][r] + bb) * vv;
  }
#pragma unroll
  for (int off = 1; off < 16; off <<= 1)
#pragma unroll
    for (int mi = 0; mi < 4; ++mi)
#pragma unroll
      for (int r = 0; r < 4; ++r)
        sc[mi][r] += __shfl_xor(sc[mi][r], off, 64);
  if (l15 == 0) {
#pragma unroll
    for (int mi = 0; mi < 4; ++mi)
#pragma unroll
      for (int r = 0; r < 4; ++r)
        scpart[wid][mi * 16 + l4 * 4 + r] = sc[mi][r];
  }
  __syncthreads();
  if (t < 64) {
    float s = 0.f;
#pragma unroll
    for (int w = 0; w < 16; ++w) s += scpart[w][t];
    scores[rowBase + t] = s;
  }
}

// ---------------- kernel 4: per-(b,m) segment softmax + pooling
__global__ __launch_bounds__(256) void pool_kernel(
    const float* __restrict__ hid, const float* __restrict__ scores,
    const unsigned char* __restrict__ segv, const int* __restrict__ nsep,
    float* __restrict__ out) {
  int bm = blockIdx.x;
  int b = bm / Mn, m = bm % Mn;
  int t = threadIdx.x;
  __shared__ float wLds[Sn];
  __shared__ float red[256];
  __shared__ int ired[256];
  const float NEG = -1e30f;

  int base = b * Sn;
  unsigned char mg = (unsigned char)m;
  unsigned char g0 = segv[base + t], g1 = segv[base + 256 + t];
  bool v0 = (g0 == mg), v1 = (g1 == mg);
  float s0 = v0 ? scores[base + t] : NEG;
  float s1 = v1 ? scores[base + 256 + t] : NEG;

  red[t] = fmaxf(s0, s1);
  __syncthreads();
  for (int o = 128; o > 0; o >>= 1) {
    if (t < o) red[t] = fmaxf(red[t], red[t + o]);
    __syncthreads();
  }
  float gmax = red[0];
  __syncthreads();

  size_t obase = (size_t)bm * Hn;
  if (gmax <= -0.5e30f) {
    int nb = nsep[b];
    float a0 = 0.f, a1 = 0.f, a2 = 0.f;
    if (m == 0 && nb == 0) {
      const float* hp = hid + (size_t)base * Hn;
      a0 = hp[t]; a1 = hp[t + 256]; a2 = hp[t + 512];
    }
    out[obase + t] = a0; out[obase + 256 + t] = a1; out[obase + 512 + t] = a2;
    return;
  }

  float e0 = v0 ? expf(s0 - gmax) : 0.f;
  float e1 = v1 ? expf(s1 - gmax) : 0.f;
  red[t] = e0 + e1;
  __syncthreads();
  for (int o = 128; o > 0; o >>= 1) {
    if (t < o) red[t] += red[t + o];
    __syncthreads();
  }
  float inv = 1.f / red[0];
  __syncthreads();
  wLds[t] = e0 * inv;
  wLds[256 + t] = e1 * inv;

  ired[t] = min(v0 ? t : 0x7fffffff, v1 ? (256 + t) : 0x7fffffff);
  __syncthreads();
  for (int o = 128; o > 0; o >>= 1) {
    if (t < o) ired[t] = min(ired[t], ired[t + o]);
    __syncthreads();
  }
  int start = ired[0];
  __syncthreads();
  ired[t] = max(v0 ? t : -1, v1 ? (256 + t) : -1);
  __syncthreads();
  for (int o = 128; o > 0; o >>= 1) {
    if (t < o) ired[t] = max(ired[t], ired[t + o]);
    __syncthreads();
  }
  int end = ired[0];
  __syncthreads();

  float a0 = 0.f, a1 = 0.f, a2 = 0.f;
  for (int s = start; s <= end; ++s) {
    float w = wLds[s];
    if (w != 0.f) {
      const float* hp = hid + (size_t)(base + s) * Hn;
      a0 += w * hp[t];
      a1 += w * hp[t + 256];
      a2 += w * hp[t + 512];
    }
  }
  out[obase + t] = a0;
  out[obase + 256 + t] = a1;
  out[obase + 512 + t] = a2;
}

// ---------------- launch
extern "C" void kernel_launch(void* const* d_in, const int* in_sizes, int n_in,
                              void* d_out, int out_size, void* d_ws, size_t ws_size,
                              hipStream_t stream) {
  const float* hidden = (const float*)d_in[0];
  const int* ids      = (const int*)d_in[1];
  const float* W      = (const float*)d_in[2];
  const float* bbias  = (const float*)d_in[3];
  const float* vvec   = (const float*)d_in[4];

  char* ws = (char*)d_ws;
  unsigned short* WBp  = (unsigned short*)(ws);            // 1,179,648 B
  float* scores        = (float*)(ws + 1179648);
  unsigned char* segv  = (unsigned char*)(ws + 1310720);
  int* nsep            = (int*)(ws + 1343488);

  convw_kernel<<<288, 256, 0, stream>>>(W, WBp);
  segscan_kernel<<<Bn, Sn, 0, stream>>>(ids, segv, nsep);
  score_gemm_kernel<<<BS / 64, 1024, 0, stream>>>(hidden, WBp, bbias, vvec, scores);
  pool_kernel<<<Bn * Mn, 256, 0, stream>>>(hidden, scores, segv, nsep, (float*)d_out);
}